// Round 3
// baseline (108.759 us; speedup 1.0000x reference)
//
#include <hip/hip_runtime.h>

#define NPTS 8192
#define TILE 128
#define TT (NPTS / TILE)            /* 64 row/col tiles           */
#define NPAIRS (TT * (TT + 1) / 2)  /* 2080 triangular tile pairs */
#define MIN_DIST 0.1f

// Single fused kernel: proximity penalty (triangular tile pairs) + MSE
// (blocks k<32). Block partial -> device-scope double atomicAdd in d_ws;
// last-arriving block writes the final f32 scalar to out.
// d_ws layout: [0..7] double accumulator, [8..11] arrival counter (both
// zeroed by a hipMemsetAsync node before this kernel).
__global__ __launch_bounds__(TILE) void pair_tiles(const float2* __restrict__ P,
                                                   const float* __restrict__ pred,
                                                   const float* __restrict__ targ,
                                                   double* __restrict__ acc_d,
                                                   unsigned* __restrict__ cnt,
                                                   float* __restrict__ out) {
    int k = blockIdx.x;

    // Triangular decode k -> (bi, bj), bi <= bj (f32 estimate + fixup).
    int bi = (int)(((float)(2 * TT + 1) -
                    sqrtf((float)((2 * TT + 1) * (2 * TT + 1) - 8 * k))) * 0.5f);
    bi = min(max(bi, 0), TT - 1);
    while (bi > 0 && (bi * TT - bi * (bi - 1) / 2) > k) --bi;
    while (((bi + 1) * TT - (bi + 1) * bi / 2) <= k) ++bi;
    int bj = bi + (k - (bi * TT - bi * (bi - 1) / 2));
    // Force SGPR so inner-loop loads are provably wave-uniform (s_load).
    bi = __builtin_amdgcn_readfirstlane(bi);
    bj = __builtin_amdgcn_readfirstlane(bj);

    int tid = threadIdx.x;
    float2 pi = P[bi * TILE + tid];
    const float4* __restrict__ q4 = (const float4*)(P + bj * TILE);  // 2 pts/load

    float acc = 0.0f;
    if (bi == bj) {
        // Diagonal tile: all ordered pairs minus i==j, halved afterwards.
#pragma unroll 8
        for (int j = 0; j < TILE / 2; ++j) {
            float4 q = q4[j];
            float dx0 = pi.x - q.x, dy0 = pi.y - q.y;
            float dx1 = pi.x - q.z, dy1 = pi.y - q.w;
            float d20 = fmaf(dy0, dy0, dx0 * dx0);
            float d21 = fmaf(dy1, dy1, dx1 * dx1);
            float t0 = fmaxf(MIN_DIST - __builtin_amdgcn_sqrtf(d20), 0.0f);
            float t1 = fmaxf(MIN_DIST - __builtin_amdgcn_sqrtf(d21), 0.0f);
            t0 = (2 * j == tid) ? 0.0f : t0;
            t1 = (2 * j + 1 == tid) ? 0.0f : t1;
            acc = fmaf(t0, t0, acc);
            acc = fmaf(t1, t1, acc);
        }
        acc *= 0.5f;
    } else {
#pragma unroll 8
        for (int j = 0; j < TILE / 2; ++j) {
            float4 q = q4[j];
            float dx0 = pi.x - q.x, dy0 = pi.y - q.y;
            float dx1 = pi.x - q.z, dy1 = pi.y - q.w;
            float d20 = fmaf(dy0, dy0, dx0 * dx0);
            float d21 = fmaf(dy1, dy1, dx1 * dx1);
            float t0 = fmaxf(MIN_DIST - __builtin_amdgcn_sqrtf(d20), 0.0f);
            float t1 = fmaxf(MIN_DIST - __builtin_amdgcn_sqrtf(d21), 0.0f);
            acc = fmaf(t0, t0, acc);
            acc = fmaf(t1, t1, acc);
        }
    }

    // MSE slice: blocks 0..31, one float4 (4 elems) per thread = 16384 elems.
    if (k < 32) {
        int idx = k * TILE + tid;  // float4 index, 0..4095
        float4 p = ((const float4*)pred)[idx];
        float4 t = ((const float4*)targ)[idx];
        float d0 = p.x - t.x, d1 = p.y - t.y, d2 = p.z - t.z, d3 = p.w - t.w;
        float m = d0 * d0;
        m = fmaf(d1, d1, m);
        m = fmaf(d2, d2, m);
        m = fmaf(d3, d3, m);
        acc = fmaf(m, 1.0f / (float)(NPTS * 2), acc);  // /16384 exact pow2
    }

    // wave (64) reduce, then cross-wave via LDS
    for (int off = 32; off > 0; off >>= 1)
        acc += __shfl_down(acc, off, 64);
    __shared__ float wsum[TILE / 64];
    int wave = tid >> 6;
    int lane = tid & 63;
    if (lane == 0) wsum[wave] = acc;
    __syncthreads();
    if (tid == 0) {
        float s = wsum[0];
#pragma unroll
        for (int w = 1; w < TILE / 64; ++w) s += wsum[w];
        // Device-scope accumulate; release, then arrive.
        atomicAdd(acc_d, (double)s);
        __threadfence();
        unsigned old = atomicAdd(cnt, 1u);
        if (old == NPAIRS - 1) {
            __threadfence();
            double tot = atomicAdd(acc_d, 0.0);  // device-scope read
            out[0] = (float)tot;
        }
    }
}

extern "C" void kernel_launch(void* const* d_in, const int* in_sizes, int n_in,
                              void* d_out, int out_size, void* d_ws, size_t ws_size,
                              hipStream_t stream) {
    const float* pred = (const float*)d_in[0];
    const float* targ = (const float*)d_in[1];
    double* acc_d = (double*)d_ws;
    unsigned* cnt = (unsigned*)((char*)d_ws + 8);

    hipMemsetAsync(d_ws, 0, 16, stream);  // zero accumulator + counter
    pair_tiles<<<NPAIRS, TILE, 0, stream>>>((const float2*)pred, pred, targ,
                                            acc_d, cnt, (float*)d_out);
}

// Round 5
// 71.032 us; speedup vs baseline: 1.5311x; 1.5311x over previous
//
#include <hip/hip_runtime.h>

#define NPTS 8192
#define TILE 128
#define TT (NPTS / TILE)            /* 64 row/col tiles           */
#define NPAIRS (TT * (TT + 1) / 2)  /* 2080 triangular tile pairs */
#define MIN_DIST 0.1f

// Proximity penalty over triangular tile pairs + fused MSE (blocks k<32).
// 1 wave per block; each thread owns TWO i-points (t and t+64), so each
// float4 j-load (2 points, wave-uniform s_load) feeds 4 pair evaluations.
// One float partial per block -> d_ws; no atomics.
__global__ __launch_bounds__(64) void pair_tiles(const float2* __restrict__ P,
                                                 const float* __restrict__ pred,
                                                 const float* __restrict__ targ,
                                                 float* __restrict__ partial) {
    int k = blockIdx.x;

    // Triangular decode k -> (bi, bj), bi <= bj (f32 estimate + fixup).
    int bi = (int)(((float)(2 * TT + 1) -
                    sqrtf((float)((2 * TT + 1) * (2 * TT + 1) - 8 * k))) * 0.5f);
    bi = min(max(bi, 0), TT - 1);
    while (bi > 0 && (bi * TT - bi * (bi - 1) / 2) > k) --bi;
    while (((bi + 1) * TT - (bi + 1) * bi / 2) <= k) ++bi;
    int bj = bi + (k - (bi * TT - bi * (bi - 1) / 2));
    // Force SGPR so the inner-loop loads are provably wave-uniform (s_load).
    bi = __builtin_amdgcn_readfirstlane(bi);
    bj = __builtin_amdgcn_readfirstlane(bj);

    int t = threadIdx.x;  // 0..63
    float2 a0 = P[bi * TILE + t];
    float2 a1 = P[bi * TILE + 64 + t];
    const float4* __restrict__ q4 = (const float4*)(P + bj * TILE);  // 2 pts/load

    float acc = 0.0f;
    if (bi == bj) {
        // Diagonal tile: all ordered pairs, mask i==j, halve afterwards.
#pragma unroll 8
        for (int jj = 0; jj < TILE / 2; ++jj) {
            float4 q = q4[jj];
            float dx0 = a0.x - q.x, dy0 = a0.y - q.y;
            float dx1 = a0.x - q.z, dy1 = a0.y - q.w;
            float dx2 = a1.x - q.x, dy2 = a1.y - q.y;
            float dx3 = a1.x - q.z, dy3 = a1.y - q.w;
            float u0 = fmaxf(MIN_DIST - __builtin_amdgcn_sqrtf(fmaf(dy0, dy0, dx0 * dx0)), 0.0f);
            float u1 = fmaxf(MIN_DIST - __builtin_amdgcn_sqrtf(fmaf(dy1, dy1, dx1 * dx1)), 0.0f);
            float u2 = fmaxf(MIN_DIST - __builtin_amdgcn_sqrtf(fmaf(dy2, dy2, dx2 * dx2)), 0.0f);
            float u3 = fmaxf(MIN_DIST - __builtin_amdgcn_sqrtf(fmaf(dy3, dy3, dx3 * dx3)), 0.0f);
            u0 = (2 * jj == t) ? 0.0f : u0;
            u1 = (2 * jj + 1 == t) ? 0.0f : u1;
            u2 = (2 * jj == 64 + t) ? 0.0f : u2;
            u3 = (2 * jj + 1 == 64 + t) ? 0.0f : u3;
            acc = fmaf(u0, u0, acc);
            acc = fmaf(u1, u1, acc);
            acc = fmaf(u2, u2, acc);
            acc = fmaf(u3, u3, acc);
        }
        acc *= 0.5f;
    } else {
#pragma unroll 8
        for (int jj = 0; jj < TILE / 2; ++jj) {
            float4 q = q4[jj];
            float dx0 = a0.x - q.x, dy0 = a0.y - q.y;
            float dx1 = a0.x - q.z, dy1 = a0.y - q.w;
            float dx2 = a1.x - q.x, dy2 = a1.y - q.y;
            float dx3 = a1.x - q.z, dy3 = a1.y - q.w;
            float u0 = fmaxf(MIN_DIST - __builtin_amdgcn_sqrtf(fmaf(dy0, dy0, dx0 * dx0)), 0.0f);
            float u1 = fmaxf(MIN_DIST - __builtin_amdgcn_sqrtf(fmaf(dy1, dy1, dx1 * dx1)), 0.0f);
            float u2 = fmaxf(MIN_DIST - __builtin_amdgcn_sqrtf(fmaf(dy2, dy2, dx2 * dx2)), 0.0f);
            float u3 = fmaxf(MIN_DIST - __builtin_amdgcn_sqrtf(fmaf(dy3, dy3, dx3 * dx3)), 0.0f);
            acc = fmaf(u0, u0, acc);
            acc = fmaf(u1, u1, acc);
            acc = fmaf(u2, u2, acc);
            acc = fmaf(u3, u3, acc);
        }
    }

    // MSE slice: blocks 0..31 cover 4096 float4; 2 float4 per thread.
    if (k < 32) {
        int base = k * 128 + t;  // float4 index
        float4 p0 = ((const float4*)pred)[base];
        float4 r0 = ((const float4*)targ)[base];
        float4 p1 = ((const float4*)pred)[base + 64];
        float4 r1 = ((const float4*)targ)[base + 64];
        float e0 = p0.x - r0.x, e1 = p0.y - r0.y, e2 = p0.z - r0.z, e3 = p0.w - r0.w;
        float e4 = p1.x - r1.x, e5 = p1.y - r1.y, e6 = p1.z - r1.z, e7 = p1.w - r1.w;
        float m = e0 * e0;
        m = fmaf(e1, e1, m);
        m = fmaf(e2, e2, m);
        m = fmaf(e3, e3, m);
        m = fmaf(e4, e4, m);
        m = fmaf(e5, e5, m);
        m = fmaf(e6, e6, m);
        m = fmaf(e7, e7, m);
        acc = fmaf(m, 1.0f / 16384.0f, acc);  // /(N*D), exact pow2
    }

    // Single-wave shuffle reduction; lane 0 stores the block partial.
    for (int off = 32; off > 0; off >>= 1)
        acc += __shfl_down(acc, off, 64);
    if (t == 0) partial[k] = acc;
}

// Final reduction: 2080 partials -> out[0], double accumulation.
__global__ __launch_bounds__(256) void finalize(const float* __restrict__ partial,
                                                float* __restrict__ out) {
    int t = threadIdx.x;
    double s = 0.0;
    for (int i = t; i < NPAIRS; i += 256) s += (double)partial[i];

    for (int off = 32; off > 0; off >>= 1) s += __shfl_down(s, off, 64);
    __shared__ double sm[4];
    if ((t & 63) == 0) sm[t >> 6] = s;
    __syncthreads();
    if (t == 0) out[0] = (float)(sm[0] + sm[1] + sm[2] + sm[3]);
}

extern "C" void kernel_launch(void* const* d_in, const int* in_sizes, int n_in,
                              void* d_out, int out_size, void* d_ws, size_t ws_size,
                              hipStream_t stream) {
    const float* pred = (const float*)d_in[0];
    const float* targ = (const float*)d_in[1];
    float* partial = (float*)d_ws;  // NPAIRS floats = 8320 B of scratch

    pair_tiles<<<NPAIRS, 64, 0, stream>>>((const float2*)pred, pred, targ, partial);
    finalize<<<1, 256, 0, stream>>>(partial, (float*)d_out);
}

// Round 9
// 70.953 us; speedup vs baseline: 1.5328x; 1.0011x over previous
//
#include <hip/hip_runtime.h>

#define NPTS 8192
#define TILE 256
#define NT (NPTS / TILE)            /* 32 row/col tiles          */
#define NPAIRS (NT * (NT + 1) / 2)  /* 528 triangular tile pairs */
#define MIN_DIST 0.1f

// Broadcast lane `lane`'s value of v across the wave via v_readlane (VALU,
// result in SGPR — no memory pipe, no waitcnt).
__device__ __forceinline__ float bcast(float v, int lane) {
    return __uint_as_float(__builtin_amdgcn_readlane(__float_as_uint(v), (unsigned)lane));
}

// Proximity penalty over 256x256 triangular tile pairs + fused MSE (k<16).
// Block = 256 threads = 4 waves. Each lane holds 4 i-points (registers) and
// ONE j-point; wave w owns j-slice [w*64, w*64+64). The j-loop broadcasts
// lane s's j-point with readlane -> inner loop has ZERO memory operations.
__global__ __launch_bounds__(256) void pair_tiles(const float2* __restrict__ P,
                                                  const float* __restrict__ pred,
                                                  const float* __restrict__ targ,
                                                  float* __restrict__ partial) {
    int k = blockIdx.x;

    // Triangular decode k -> (bi, bj), bi <= bj (f32 estimate + fixup).
    int bi = (int)(((float)(2 * NT + 1) -
                    sqrtf((float)((2 * NT + 1) * (2 * NT + 1) - 8 * k))) * 0.5f);
    bi = min(max(bi, 0), NT - 1);
    while (bi > 0 && (bi * NT - bi * (bi - 1) / 2) > k) --bi;
    while (((bi + 1) * NT - (bi + 1) * bi / 2) <= k) ++bi;
    int bj = bi + (k - (bi * NT - bi * (bi - 1) / 2));
    bi = __builtin_amdgcn_readfirstlane(bi);
    bj = __builtin_amdgcn_readfirstlane(bj);

    int tid = threadIdx.x;
    int w = tid >> 6;   // wave 0..3
    int l = tid & 63;   // lane 0..63

    // Four i-points per lane (i = bi*TILE + 64*r + l covers all 256 i per wave).
    float2 a0 = P[bi * TILE + l];
    float2 a1 = P[bi * TILE + 64 + l];
    float2 a2 = P[bi * TILE + 128 + l];
    float2 a3 = P[bi * TILE + 192 + l];
    // One j-point per lane: wave w's 64-j slice.
    float2 pj = P[bj * TILE + w * 64 + l];

    bool diag = (bi == bj);
    float acc = 0.0f;

#pragma unroll 8
    for (int s = 0; s < 64; ++s) {
        float qx = bcast(pj.x, s);
        float qy = bcast(pj.y, s);

        float dx0 = a0.x - qx, dy0 = a0.y - qy;
        float dx1 = a1.x - qx, dy1 = a1.y - qy;
        float dx2 = a2.x - qx, dy2 = a2.y - qy;
        float dx3 = a3.x - qx, dy3 = a3.y - qy;
        float u0 = fmaxf(MIN_DIST - __builtin_amdgcn_sqrtf(fmaf(dy0, dy0, dx0 * dx0)), 0.0f);
        float u1 = fmaxf(MIN_DIST - __builtin_amdgcn_sqrtf(fmaf(dy1, dy1, dx1 * dx1)), 0.0f);
        float u2 = fmaxf(MIN_DIST - __builtin_amdgcn_sqrtf(fmaf(dy2, dy2, dx2 * dx2)), 0.0f);
        float u3 = fmaxf(MIN_DIST - __builtin_amdgcn_sqrtf(fmaf(dy3, dy3, dx3 * dx3)), 0.0f);
        if (diag) {
            // i == j iff (r == w) && (l == s): zero that lane's term.
            if (w == 0) u0 = (l == s) ? 0.0f : u0;
            if (w == 1) u1 = (l == s) ? 0.0f : u1;
            if (w == 2) u2 = (l == s) ? 0.0f : u2;
            if (w == 3) u3 = (l == s) ? 0.0f : u3;
        }
        acc = fmaf(u0, u0, acc);
        acc = fmaf(u1, u1, acc);
        acc = fmaf(u2, u2, acc);
        acc = fmaf(u3, u3, acc);
    }
    if (diag) acc *= 0.5f;  // diagonal tile counted each unordered pair twice

    // MSE slice: blocks 0..15 cover 4096 float4 (16384 elems), 1 per thread.
    if (k < 16) {
        int idx = k * 256 + tid;  // float4 index
        float4 p = ((const float4*)pred)[idx];
        float4 t = ((const float4*)targ)[idx];
        float e0 = p.x - t.x, e1 = p.y - t.y, e2 = p.z - t.z, e3 = p.w - t.w;
        float m = e0 * e0;
        m = fmaf(e1, e1, m);
        m = fmaf(e2, e2, m);
        m = fmaf(e3, e3, m);
        acc = fmaf(m, 1.0f / 16384.0f, acc);  // /(N*D), exact pow2
    }

    // Wave reduce then cross-wave via LDS; one float partial per block.
    for (int off = 32; off > 0; off >>= 1)
        acc += __shfl_down(acc, off, 64);
    __shared__ float wsum[4];
    if (l == 0) wsum[w] = acc;
    __syncthreads();
    if (tid == 0) partial[k] = wsum[0] + wsum[1] + wsum[2] + wsum[3];
}

// Final reduction: 528 partials -> out[0], double accumulation.
__global__ __launch_bounds__(256) void finalize(const float* __restrict__ partial,
                                                float* __restrict__ out) {
    int t = threadIdx.x;
    double s = 0.0;
    for (int i = t; i < NPAIRS; i += 256) s += (double)partial[i];

    for (int off = 32; off > 0; off >>= 1) s += __shfl_down(s, off, 64);
    __shared__ double sm[4];
    if ((t & 63) == 0) sm[t >> 6] = s;
    __syncthreads();
    if (t == 0) out[0] = (float)(sm[0] + sm[1] + sm[2] + sm[3]);
}

extern "C" void kernel_launch(void* const* d_in, const int* in_sizes, int n_in,
                              void* d_out, int out_size, void* d_ws, size_t ws_size,
                              hipStream_t stream) {
    const float* pred = (const float*)d_in[0];
    const float* targ = (const float*)d_in[1];
    float* partial = (float*)d_ws;  // NPAIRS floats of scratch

    pair_tiles<<<NPAIRS, 256, 0, stream>>>((const float2*)pred, pred, targ, partial);
    finalize<<<1, 256, 0, stream>>>(partial, (float*)d_out);
}